// Round 5
// baseline (408.424 us; speedup 1.0000x reference)
//
#include <hip/hip_runtime.h>
#include <stdint.h>

#define IN_DIM 512
#define NT 64
#define AH 128
#define NCLS 10
#define BN_EPS_C 1e-5f
#define SHRINK 0.3f
#define DSTRIDE 67  // decw leading dim (67%32=3): halved conflicts vs 66 (R2->R3)

typedef __bf16 bf16x8 __attribute__((ext_vector_type(8)));
typedef float f32x4 __attribute__((ext_vector_type(4)));
typedef unsigned int u32x4 __attribute__((ext_vector_type(4)));

__device__ __forceinline__ unsigned short f2bf(float f) {
  unsigned u = __builtin_bit_cast(unsigned, f);
  u += 0x7fffu + ((u >> 16) & 1u);   // RNE; inputs are NaN-free after NaN-zeroing
  return (unsigned short)(u >> 16);
}

__device__ __forceinline__ float bflo(unsigned w) {
  return __builtin_bit_cast(float, w << 16);
}
__device__ __forceinline__ float bfhi(unsigned w) {
  return __builtin_bit_cast(float, w & 0xffff0000u);
}

__device__ __forceinline__ void gload_lds16(const void* g, void* l) {
  __builtin_amdgcn_global_load_lds(
      (const __attribute__((address_space(1))) void*)g,
      (__attribute__((address_space(3))) void*)l, 16, 0, 0);
}

// read one 16B MFMA fragment from a swizzled [rows][64] bf16 LDS tile
__device__ __forceinline__ bf16x8 frag_ld(const char* lds, int r, int q) {
  return *reinterpret_cast<const bf16x8*>(lds + r * 128 + ((q ^ (r & 7)) * 16));
}

// ---------------- fused prep: x->bf16+flags, tree_w->bf16(pad), w1->w1t ----
__global__ void __launch_bounds__(256) k_prep(
    const float* __restrict__ x, unsigned short* __restrict__ xc, float* __restrict__ flags,
    const float* __restrict__ tw, unsigned short* __restrict__ twb,
    const float* __restrict__ w1, unsigned short* __restrict__ w1t) {
  int b = blockIdx.x;
  if (b < 4096) {
    int wid = threadIdx.x >> 6, lane = threadIdx.x & 63;
    int row = b * 4 + wid;
    const float* px = x + row * IN_DIM + lane * 8;
    float4 a = *(const float4*)px;
    float4 bb = *(const float4*)(px + 4);
    float v[8] = {a.x, a.y, a.z, a.w, bb.x, bb.y, bb.z, bb.w};
    bool nan_any = false;
    union { unsigned short s[8]; u32x4 u; } pk;
#pragma unroll
    for (int i = 0; i < 8; i++) {
      bool n = (v[i] != v[i]);
      nan_any |= n;
      pk.s[i] = f2bf(n ? 0.f : v[i]);
    }
    *reinterpret_cast<u32x4*>(xc + row * IN_DIM + lane * 8) = pk.u;
    unsigned long long bal = __ballot(nan_any);
    if (lane == 0) flags[row] = bal ? 1.f : 0.f;
  } else if (b < 5120) {
    int tid = (b - 4096) * 256 + threadIdx.x;  // 262144
    int o = tid * 8;
    int k = o & 511;
    int nt = o >> 9;
    int node = nt & 63, t = nt >> 6;
    union { unsigned short s[8]; u32x4 u; } pk;
    if (node < 63) {
      const float* p = tw + ((t * 63 + node) * 512 + k);
      float4 a = *(const float4*)p, bb = *(const float4*)(p + 4);
      float v[8] = {a.x, a.y, a.z, a.w, bb.x, bb.y, bb.z, bb.w};
#pragma unroll
      for (int i = 0; i < 8; i++) pk.s[i] = f2bf(v[i]);
    } else {
#pragma unroll
      for (int i = 0; i < 8; i++) pk.s[i] = 0;
    }
    *reinterpret_cast<u32x4*>(twb + o) = pk.u;
  } else {
    int tid = (b - 5120) * 256 + threadIdx.x;  // 65536
    int k = tid & 511, n = tid >> 9;
    w1t[n * 512 + k] = f2bf(w1[k * 128 + n]);
  }
}

// ---------------- attention ----------------

// h = BN(relu(x@w1 + b1)) : M=16384 N=128 K=512, tile 64x128
__global__ void __launch_bounds__(256) k_attn1(
    const unsigned short* __restrict__ xc, const unsigned short* __restrict__ w1t,
    const float* __restrict__ b1, const float* __restrict__ gam,
    const float* __restrict__ bet, const float* __restrict__ mu,
    const float* __restrict__ var, float* __restrict__ h) {
  __shared__ __align__(16) char smem[24576];
  char* As = smem;          // 64x64 bf16 = 8192
  char* Bs = smem + 8192;   // 128x64 bf16 = 16384
  int lane = threadIdx.x & 63, wid = threadIdx.x >> 6;
  int bm0 = blockIdx.x * 64;
  int m = lane & 15, q = lane >> 4;
  int sub = lane >> 3, cpos = lane & 7;
  f32x4 acc[8];
#pragma unroll
  for (int j = 0; j < 8; j++) acc[j] = f32x4{0.f, 0.f, 0.f, 0.f};
  const unsigned short* Ag = xc + (size_t)bm0 * 512;

  for (int ko = 0; ko < 8; ++ko) {
    const unsigned short* Ak = Ag + ko * 64;
    const unsigned short* Bk = w1t + ko * 64;
#pragma unroll
    for (int i = 0; i < 2; i++) {
      int seg = wid * 2 + i;
      int r = seg * 8 + sub;
      int cg = cpos ^ (r & 7);
      gload_lds16(Ak + r * 512 + cg * 8, As + seg * 1024);
    }
#pragma unroll
    for (int i = 0; i < 4; i++) {
      int seg = wid * 4 + i;
      int r = seg * 8 + sub;
      int cg = cpos ^ (r & 7);
      gload_lds16(Bk + r * 512 + cg * 8, Bs + seg * 1024);
    }
    __syncthreads();
#pragma unroll
    for (int ks = 0; ks < 2; ++ks) {
      bf16x8 af = frag_ld(As, wid * 16 + m, ks * 4 + q);
#pragma unroll
      for (int ni = 0; ni < 8; ni++) {
        bf16x8 bfr = frag_ld(Bs, ni * 16 + m, ks * 4 + q);
        acc[ni] = __builtin_amdgcn_mfma_f32_16x16x32_bf16(af, bfr, acc[ni], 0, 0, 0);
      }
    }
    __syncthreads();
  }
#pragma unroll
  for (int ni = 0; ni < 8; ni++) {
    int col = ni * 16 + m;
    float bb = b1[col], ga = gam[col], be = bet[col], mm = mu[col];
    float iv = rsqrtf(var[col] + BN_EPS_C);
#pragma unroll
    for (int r4 = 0; r4 < 4; r4++) {
      int row = bm0 + wid * 16 + q * 4 + r4;
      float v = acc[ni][r4] + bb;
      v = fmaxf(v, 0.f);
      v = (v - mm) * iv * ga + be;
      h[row * AH + col] = v;
    }
  }
}

// attn = softmax(h@w2 + b2); wbt = attn * SHRINK * rw
__global__ void __launch_bounds__(256) k_attn2(
    const float* __restrict__ h, const float* __restrict__ w2,
    const float* __restrict__ b2, const float* __restrict__ rw,
    float* __restrict__ wbt) {
  __shared__ float w2s[AH * NT];
  __shared__ float hs[4][AH];
  int lane = threadIdx.x & 63, wid = threadIdx.x >> 6;
  for (int i = threadIdx.x; i < AH * NT; i += 256) w2s[i] = w2[i];
  __syncthreads();
  float bb = b2[lane];
  float cf = SHRINK * rw[lane];
  for (int rr = 0; rr < 4; ++rr) {
    int row = blockIdx.x * 16 + wid * 4 + rr;
    float2 hv = *(const float2*)(h + row * AH + lane * 2);
    hs[wid][lane * 2] = hv.x;
    hs[wid][lane * 2 + 1] = hv.y;
    __syncthreads();
    float s = bb;
#pragma unroll 8
    for (int k = 0; k < AH; k++) s = fmaf(hs[wid][k], w2s[k * NT + lane], s);
    float mx = s;
#pragma unroll
    for (int o = 1; o < 64; o <<= 1) mx = fmaxf(mx, __shfl_xor(mx, o));
    float e = __expf(s - mx);
    float sm = e;
#pragma unroll
    for (int o = 1; o < 64; o <<= 1) sm += __shfl_xor(sm, o);
    wbt[row * NT + lane] = (e / sm) * cf;
    __syncthreads();
  }
}

// ---------------- main: tree logits + routing + leaf -> per-slice partials ----
// tile: 128 rows x 128 cols (2 trees), BK=64, 4 waves, SINGLE GEMM pass
// (round 4's 2-pass loop entangled live ranges -> 232 VGPR -> 11.7% occupancy).
// NO atomics (round 3: 10.5M device atomics = +300 MB WRITE, serialized at L3):
// halves combined in LDS, one bf16 partial row per block -> part[16384][32][10].
// NOTE: no min-waves arg in launch_bounds — a VGPR cap of 64 spills the
// 64-VGPR accumulator to scratch (round 2: WRITE_SIZE 102->327 MB, 1.6x slower).
__global__ void __launch_bounds__(256) k_trees(
    const unsigned short* __restrict__ xc,   // [16384][512]
    const unsigned short* __restrict__ twb,  // [64*64][512]
    const float* __restrict__ tree_b,        // [64][63]
    const float* __restrict__ tree_temp,     // [64]
    const float* __restrict__ leaf,          // [64][64][10]
    const float* __restrict__ wbt,           // [16384][64]
    const float* __restrict__ flags,         // [16384]
    unsigned short* __restrict__ part) {     // [16384][32][10] bf16
  __shared__ __align__(16) char smem[40448];
  char* As = smem;                                  // 128x64 bf16 = 16384
  char* Bs = smem + 16384;                          // 128x64 bf16 = 16384
  float* decw = reinterpret_cast<float*>(smem);     // 128 x 67 f32 = 34304 (epilogue)
  float* leaf_s = reinterpret_cast<float*>(smem + 34304);  // 2x64x12 f32 (disjoint!)
  int lane = threadIdx.x & 63, wid = threadIdx.x >> 6;
  int bm0 = blockIdx.x * 128;
  int t0 = blockIdx.y * 2;   // 2 trees per block
  int m = lane & 15, q = lane >> 4;
  int sub = lane >> 3, cpos = lane & 7;
  int rA0 = wid * 32 + m;
  int row_l = threadIdx.x & 127;
  int h = __builtin_amdgcn_readfirstlane((int)(threadIdx.x >> 7));  // wave-uniform half
  int grow = bm0 + row_l;

  // stage leaf values (12-float padded for aligned float4 reads); region is
  // disjoint from As/Bs so it can overlap the GEMM; post-GEMM barrier covers it
  for (int i = threadIdx.x; i < 1280; i += 256) {
    int tt = i / 640, rem = i - tt * 640;
    int l = rem / 10, c = rem - l * 10;
    leaf_s[tt * 768 + l * 12 + c] = leaf[t0 * 640 + i];
  }

  f32x4 acc[2][8];
#pragma unroll
  for (int i = 0; i < 2; i++)
#pragma unroll
    for (int j = 0; j < 8; j++) acc[i][j] = f32x4{0.f, 0.f, 0.f, 0.f};

  const unsigned short* Ag = xc + (size_t)bm0 * 512;
  const unsigned short* Bg = twb + (size_t)t0 * 64 * 512;

  for (int ko = 0; ko < 8; ++ko) {
    const unsigned short* Ak = Ag + ko * 64;
    const unsigned short* Bk = Bg + ko * 64;
#pragma unroll
    for (int i = 0; i < 4; i++) {
      int seg = wid * 4 + i;
      int r = seg * 8 + sub;
      int cg = cpos ^ (r & 7);
      gload_lds16(Ak + r * 512 + cg * 8, As + seg * 1024);
      gload_lds16(Bk + r * 512 + cg * 8, Bs + seg * 1024);
    }
    __syncthreads();
#pragma unroll
    for (int ks = 0; ks < 2; ++ks) {
      bf16x8 af[2];
#pragma unroll
      for (int mi = 0; mi < 2; mi++) af[mi] = frag_ld(As, rA0 + mi * 16, ks * 4 + q);
#pragma unroll
      for (int ni = 0; ni < 8; ni++) {
        bf16x8 bfr = frag_ld(Bs, ni * 16 + m, ks * 4 + q);
#pragma unroll
        for (int mi = 0; mi < 2; mi++)
          acc[mi][ni] = __builtin_amdgcn_mfma_f32_16x16x32_bf16(af[mi], bfr, acc[mi][ni], 0, 0, 0);
      }
    }
    __syncthreads();
  }

  // ---- epilogue ----
  bool miss = flags[grow] != 0.f;
  float pc[10];
#pragma unroll
  for (int c = 0; c < 10; c++) pc[c] = 0.f;

  for (int tt = 0; tt < 2; ++tt) {
    int t = t0 + tt;
    float itemp = 1.f / tree_temp[t];
    float tbv[4];
#pragma unroll
    for (int nl = 0; nl < 4; nl++) {
      int node = nl * 16 + m;
      tbv[nl] = (node < 63) ? tree_b[t * 63 + node] : 0.f;
    }
    __syncthreads();  // previous readers of decw (GEMM tiles / routing) done
    // sigmoid decisions -> LDS, level-grouped offset node+1
#pragma unroll
    for (int mi = 0; mi < 2; mi++) {
#pragma unroll
      for (int nl = 0; nl < 4; nl++) {
        int node = nl * 16 + m;
        f32x4 a = acc[mi][tt * 4 + nl];
#pragma unroll
        for (int r4 = 0; r4 < 4; r4++) {
          int row = wid * 32 + mi * 16 + q * 4 + r4;
          float z = (a[r4] + tbv[nl]) * itemp;
          decw[row * DSTRIDE + node + 1] = __builtin_amdgcn_rcpf(1.f + __expf(-z));
        }
      }
    }
    __syncthreads();

    const float* dr = decw + row_l * DSTRIDE;
    float R[16];
    {
      float d0 = dr[1];
      d0 = miss ? 0.5f : d0;
      R[0] = d0;
      R[1] = 1.f - d0;
    }
#pragma unroll
    for (int L = 1; L <= 3; ++L) {
      int half = 1 << L;
#pragma unroll
      for (int g = 0; g < half; g += 2) {
        float da = dr[half + g];
        float db = dr[half + g + 1];
        da = miss ? 0.5f : da;
        db = miss ? 0.5f : db;
        float ra = R[g] * da;
        R[g + half] = R[g] - ra;
        R[g] = ra;
        float rb = R[g + 1] * db;
        R[g + 1 + half] = R[g + 1] - rb;
        R[g + 1] = rb;
      }
    }
    // level 4: keep only children with bit4 == h
#pragma unroll
    for (int p = 0; p < 16; p++) {
      float da = dr[16 + p];
      da = miss ? 0.5f : da;
      da = h ? (1.f - da) : da;
      R[p] *= da;
    }
    // level 5 + leaf dot from LDS (vectorized aligned reads, 12-float stride)
    float a10[10];
#pragma unroll
    for (int c = 0; c < 10; c++) a10[c] = 0.f;
    const float* Lf = leaf_s + tt * 768 + 192 * h;
#pragma unroll
    for (int p = 0; p < 16; p++) {
      float da = dr[32 + 16 * h + p];
      da = miss ? 0.5f : da;
      float rl = R[p] * da, rr = R[p] - rl;
      float4 La0 = *(const float4*)(Lf + p * 12);
      float4 La1 = *(const float4*)(Lf + p * 12 + 4);
      float2 La2 = *(const float2*)(Lf + p * 12 + 8);
      float4 Lb0 = *(const float4*)(Lf + 384 + p * 12);
      float4 Lb1 = *(const float4*)(Lf + 384 + p * 12 + 4);
      float2 Lb2 = *(const float2*)(Lf + 384 + p * 12 + 8);
      a10[0] = fmaf(rl, La0.x, fmaf(rr, Lb0.x, a10[0]));
      a10[1] = fmaf(rl, La0.y, fmaf(rr, Lb0.y, a10[1]));
      a10[2] = fmaf(rl, La0.z, fmaf(rr, Lb0.z, a10[2]));
      a10[3] = fmaf(rl, La0.w, fmaf(rr, Lb0.w, a10[3]));
      a10[4] = fmaf(rl, La1.x, fmaf(rr, Lb1.x, a10[4]));
      a10[5] = fmaf(rl, La1.y, fmaf(rr, Lb1.y, a10[5]));
      a10[6] = fmaf(rl, La1.z, fmaf(rr, Lb1.z, a10[6]));
      a10[7] = fmaf(rl, La1.w, fmaf(rr, Lb1.w, a10[7]));
      a10[8] = fmaf(rl, La2.x, fmaf(rr, Lb2.x, a10[8]));
      a10[9] = fmaf(rl, La2.y, fmaf(rr, Lb2.y, a10[9]));
    }
    float w = wbt[grow * 64 + t];
#pragma unroll
    for (int c = 0; c < 10; c++) pc[c] = fmaf(w, a10[c], pc[c]);
  }

  // ---- combine halves in LDS, one non-atomic bf16 partial row per block ----
  __syncthreads();
  float* redbuf = reinterpret_cast<float*>(smem);  // 128 x 10 f32
  if (h == 1) {
#pragma unroll
    for (int c = 0; c < 10; c++) redbuf[row_l * 10 + c] = pc[c];
  }
  __syncthreads();
  if (h == 0) {
    unsigned short* po = part + ((size_t)grow * 32 + blockIdx.y) * 10;
    unsigned wdw[5];
#pragma unroll
    for (int k = 0; k < 5; k++) {
      unsigned lo = f2bf(pc[2 * k] + redbuf[row_l * 10 + 2 * k]);
      unsigned hi = f2bf(pc[2 * k + 1] + redbuf[row_l * 10 + 2 * k + 1]);
      wdw[k] = lo | (hi << 16);
    }
    unsigned* pu = reinterpret_cast<unsigned*>(po);
#pragma unroll
    for (int k = 0; k < 5; k++) pu[k] = wdw[k];
  }
}

// ---------------- final: reduce 32 bf16 slices + softmax ----------------
__global__ void __launch_bounds__(256) k_finish(const unsigned short* __restrict__ part,
                                               float* __restrict__ out) {
  int row = blockIdx.x * 256 + threadIdx.x;
  const unsigned* pu = reinterpret_cast<const unsigned*>(part) + (size_t)row * 160;
  float v[10];
#pragma unroll
  for (int c = 0; c < 10; c++) v[c] = 0.f;
#pragma unroll 4
  for (int s = 0; s < 32; ++s) {
#pragma unroll
    for (int k = 0; k < 5; k++) {
      unsigned wv = pu[s * 5 + k];
      v[2 * k] += bflo(wv);
      v[2 * k + 1] += bfhi(wv);
    }
  }
  float mx = -1e30f;
#pragma unroll
  for (int c = 0; c < 10; c++) mx = fmaxf(mx, v[c]);
  float sm = 0.f;
#pragma unroll
  for (int c = 0; c < 10; c++) {
    v[c] = __expf(v[c] - mx);
    sm += v[c];
  }
  float inv = 1.f / sm;
#pragma unroll
  for (int c = 0; c < 10; c++) out[row * 10 + c] = v[c] * inv;
}

extern "C" void kernel_launch(void* const* d_in, const int* in_sizes, int n_in,
                              void* d_out, int out_size, void* d_ws, size_t ws_size,
                              hipStream_t stream) {
  const float* x    = (const float*)d_in[0];
  const float* w1   = (const float*)d_in[1];
  const float* b1   = (const float*)d_in[2];
  const float* gam  = (const float*)d_in[3];
  const float* bet  = (const float*)d_in[4];
  const float* mu   = (const float*)d_in[5];
  const float* var  = (const float*)d_in[6];
  const float* w2   = (const float*)d_in[7];
  const float* b2   = (const float*)d_in[8];
  const float* tw   = (const float*)d_in[9];
  const float* tb   = (const float*)d_in[10];
  const float* temp = (const float*)d_in[11];
  const float* leaf = (const float*)d_in[12];
  const float* rw   = (const float*)d_in[13];
  float* out = (float*)d_out;

  char* ws = (char*)d_ws;
  unsigned short* xc  = (unsigned short*)(ws);             // 16,777,216 B
  unsigned short* twb = (unsigned short*)(ws + 16777216);  //  4,194,304 B
  unsigned short* w1t = (unsigned short*)(ws + 20971520);  //    131,072 B
  float* wbt  = (float*)(ws + 21102592);                   //  4,194,304 B
  float* flg  = (float*)(ws + 25296896);                   //     65,536 B
  float* h    = (float*)(ws + 25362432);                   //  8,388,608 B (dead after attn2)
  unsigned short* part = (unsigned short*)(ws + 25362432); // 10,485,760 B (overlaps h)

  k_prep<<<5376, 256, 0, stream>>>(x, xc, flg, tw, twb, w1, w1t);
  k_attn1<<<256, 256, 0, stream>>>(xc, w1t, b1, gam, bet, mu, var, h);
  k_attn2<<<1024, 256, 0, stream>>>(h, w2, b2, rw, wbt);
  dim3 g2(128, 32);
  k_trees<<<g2, 256, 0, stream>>>(xc, twb, tb, temp, leaf, wbt, flg, part);
  k_finish<<<64, 256, 0, stream>>>(part, out);
}

// Round 6
// 321.778 us; speedup vs baseline: 1.2693x; 1.2693x over previous
//
#include <hip/hip_runtime.h>
#include <stdint.h>

#define IN_DIM 512
#define NT 64
#define AH 128
#define NCLS 10
#define BN_EPS_C 1e-5f
#define SHRINK 0.3f
#define DSTRIDE 67  // decw leading dim (67%32=3)

typedef __bf16 bf16x8 __attribute__((ext_vector_type(8)));
typedef float f32x4 __attribute__((ext_vector_type(4)));
typedef unsigned int u32x4 __attribute__((ext_vector_type(4)));

__device__ __forceinline__ unsigned short f2bf(float f) {
  unsigned u = __builtin_bit_cast(unsigned, f);
  u += 0x7fffu + ((u >> 16) & 1u);   // RNE; inputs are NaN-free after NaN-zeroing
  return (unsigned short)(u >> 16);
}

__device__ __forceinline__ float bflo(unsigned w) {
  return __builtin_bit_cast(float, w << 16);
}
__device__ __forceinline__ float bfhi(unsigned w) {
  return __builtin_bit_cast(float, w & 0xffff0000u);
}

__device__ __forceinline__ void gload_lds16(const void* g, void* l) {
  __builtin_amdgcn_global_load_lds(
      (const __attribute__((address_space(1))) void*)g,
      (__attribute__((address_space(3))) void*)l, 16, 0, 0);
}

// read one 16B MFMA fragment from a swizzled [rows][64] bf16 LDS tile
__device__ __forceinline__ bf16x8 frag_ld(const char* lds, int r, int q) {
  return *reinterpret_cast<const bf16x8*>(lds + r * 128 + ((q ^ (r & 7)) * 16));
}

// ---------------- fused prep: x->bf16+flags, tree_w->bf16(pad), w1->w1t ----
__global__ void __launch_bounds__(256) k_prep(
    const float* __restrict__ x, unsigned short* __restrict__ xc, float* __restrict__ flags,
    const float* __restrict__ tw, unsigned short* __restrict__ twb,
    const float* __restrict__ w1, unsigned short* __restrict__ w1t) {
  int b = blockIdx.x;
  if (b < 4096) {
    int wid = threadIdx.x >> 6, lane = threadIdx.x & 63;
    int row = b * 4 + wid;
    const float* px = x + row * IN_DIM + lane * 8;
    float4 a = *(const float4*)px;
    float4 bb = *(const float4*)(px + 4);
    float v[8] = {a.x, a.y, a.z, a.w, bb.x, bb.y, bb.z, bb.w};
    bool nan_any = false;
    union { unsigned short s[8]; u32x4 u; } pk;
#pragma unroll
    for (int i = 0; i < 8; i++) {
      bool n = (v[i] != v[i]);
      nan_any |= n;
      pk.s[i] = f2bf(n ? 0.f : v[i]);
    }
    *reinterpret_cast<u32x4*>(xc + row * IN_DIM + lane * 8) = pk.u;
    unsigned long long bal = __ballot(nan_any);
    if (lane == 0) flags[row] = bal ? 1.f : 0.f;
  } else if (b < 5120) {
    int tid = (b - 4096) * 256 + threadIdx.x;  // 262144
    int o = tid * 8;
    int k = o & 511;
    int nt = o >> 9;
    int node = nt & 63, t = nt >> 6;
    union { unsigned short s[8]; u32x4 u; } pk;
    if (node < 63) {
      const float* p = tw + ((t * 63 + node) * 512 + k);
      float4 a = *(const float4*)p, bb = *(const float4*)(p + 4);
      float v[8] = {a.x, a.y, a.z, a.w, bb.x, bb.y, bb.z, bb.w};
#pragma unroll
      for (int i = 0; i < 8; i++) pk.s[i] = f2bf(v[i]);
    } else {
#pragma unroll
      for (int i = 0; i < 8; i++) pk.s[i] = 0;
    }
    *reinterpret_cast<u32x4*>(twb + o) = pk.u;
  } else {
    int tid = (b - 5120) * 256 + threadIdx.x;  // 65536
    int k = tid & 511, n = tid >> 9;
    w1t[n * 512 + k] = f2bf(w1[k * 128 + n]);
  }
}

// ---------------- attention ----------------

// h = BN(relu(x@w1 + b1)) : M=16384 N=128 K=512, tile 64x128
__global__ void __launch_bounds__(256) k_attn1(
    const unsigned short* __restrict__ xc, const unsigned short* __restrict__ w1t,
    const float* __restrict__ b1, const float* __restrict__ gam,
    const float* __restrict__ bet, const float* __restrict__ mu,
    const float* __restrict__ var, float* __restrict__ h) {
  __shared__ __align__(16) char smem[24576];
  char* As = smem;          // 64x64 bf16 = 8192
  char* Bs = smem + 8192;   // 128x64 bf16 = 16384
  int lane = threadIdx.x & 63, wid = threadIdx.x >> 6;
  int bm0 = blockIdx.x * 64;
  int m = lane & 15, q = lane >> 4;
  int sub = lane >> 3, cpos = lane & 7;
  f32x4 acc[8];
#pragma unroll
  for (int j = 0; j < 8; j++) acc[j] = f32x4{0.f, 0.f, 0.f, 0.f};
  const unsigned short* Ag = xc + (size_t)bm0 * 512;

  for (int ko = 0; ko < 8; ++ko) {
    const unsigned short* Ak = Ag + ko * 64;
    const unsigned short* Bk = w1t + ko * 64;
#pragma unroll
    for (int i = 0; i < 2; i++) {
      int seg = wid * 2 + i;
      int r = seg * 8 + sub;
      int cg = cpos ^ (r & 7);
      gload_lds16(Ak + r * 512 + cg * 8, As + seg * 1024);
    }
#pragma unroll
    for (int i = 0; i < 4; i++) {
      int seg = wid * 4 + i;
      int r = seg * 8 + sub;
      int cg = cpos ^ (r & 7);
      gload_lds16(Bk + r * 512 + cg * 8, Bs + seg * 1024);
    }
    __syncthreads();
#pragma unroll
    for (int ks = 0; ks < 2; ++ks) {
      bf16x8 af = frag_ld(As, wid * 16 + m, ks * 4 + q);
#pragma unroll
      for (int ni = 0; ni < 8; ni++) {
        bf16x8 bfr = frag_ld(Bs, ni * 16 + m, ks * 4 + q);
        acc[ni] = __builtin_amdgcn_mfma_f32_16x16x32_bf16(af, bfr, acc[ni], 0, 0, 0);
      }
    }
    __syncthreads();
  }
#pragma unroll
  for (int ni = 0; ni < 8; ni++) {
    int col = ni * 16 + m;
    float bb = b1[col], ga = gam[col], be = bet[col], mm = mu[col];
    float iv = rsqrtf(var[col] + BN_EPS_C);
#pragma unroll
    for (int r4 = 0; r4 < 4; r4++) {
      int row = bm0 + wid * 16 + q * 4 + r4;
      float v = acc[ni][r4] + bb;
      v = fmaxf(v, 0.f);
      v = (v - mm) * iv * ga + be;
      h[row * AH + col] = v;
    }
  }
}

// attn = softmax(h@w2 + b2); wbt = attn * SHRINK * rw
__global__ void __launch_bounds__(256) k_attn2(
    const float* __restrict__ h, const float* __restrict__ w2,
    const float* __restrict__ b2, const float* __restrict__ rw,
    float* __restrict__ wbt) {
  __shared__ float w2s[AH * NT];
  __shared__ float hs[4][AH];
  int lane = threadIdx.x & 63, wid = threadIdx.x >> 6;
  for (int i = threadIdx.x; i < AH * NT; i += 256) w2s[i] = w2[i];
  __syncthreads();
  float bb = b2[lane];
  float cf = SHRINK * rw[lane];
  for (int rr = 0; rr < 4; ++rr) {
    int row = blockIdx.x * 16 + wid * 4 + rr;
    float2 hv = *(const float2*)(h + row * AH + lane * 2);
    hs[wid][lane * 2] = hv.x;
    hs[wid][lane * 2 + 1] = hv.y;
    __syncthreads();
    float s = bb;
#pragma unroll 8
    for (int k = 0; k < AH; k++) s = fmaf(hs[wid][k], w2s[k * NT + lane], s);
    float mx = s;
#pragma unroll
    for (int o = 1; o < 64; o <<= 1) mx = fmaxf(mx, __shfl_xor(mx, o));
    float e = __expf(s - mx);
    float sm = e;
#pragma unroll
    for (int o = 1; o < 64; o <<= 1) sm += __shfl_xor(sm, o);
    wbt[row * NT + lane] = (e / sm) * cf;
    __syncthreads();
  }
}

// ---------------- main: tree logits + routing + leaf -> per-slice partials ----
// tile: 128 rows x 128 cols (2 trees), BK=64, 4 waves, SINGLE GEMM pass.
// Epilogue: decisions via LDS (stride 67); LEAF VALUES VIA WAVE-UNIFORM GLOBAL
// READS -> compiler puts them in SGPRs (round 3 compiled this shape to 92 VGPR;
// round 5's LDS-float4 leaf reads blew it to 216 VGPR -> 1 block/CU).
// NO atomics (round 3: 10.5M device atomics = +300 MB WRITE, serialized at L3):
// halves combined in LDS, one bf16 partial row per block -> part[16384][32][10].
// NOTE: no min-waves arg in launch_bounds — a VGPR cap of 64 spills the
// 64-VGPR accumulator to scratch (round 2: WRITE_SIZE 102->327 MB, 1.6x slower).
__global__ void __launch_bounds__(256) k_trees(
    const unsigned short* __restrict__ xc,   // [16384][512]
    const unsigned short* __restrict__ twb,  // [64*64][512]
    const float* __restrict__ tree_b,        // [64][63]
    const float* __restrict__ tree_temp,     // [64]
    const float* __restrict__ leaf,          // [64][64][10]
    const float* __restrict__ wbt,           // [16384][64]
    const float* __restrict__ flags,         // [16384]
    unsigned short* __restrict__ part) {     // [16384][32][10] bf16
  __shared__ __align__(16) char smem[34816];
  char* As = smem;                                  // 128x64 bf16 = 16384
  char* Bs = smem + 16384;                          // 128x64 bf16 = 16384
  float* decw = reinterpret_cast<float*>(smem);     // 128 x 67 f32 = 34304 (epilogue)
  int lane = threadIdx.x & 63, wid = threadIdx.x >> 6;
  int bm0 = blockIdx.x * 128;
  int t0 = blockIdx.y * 2;   // 2 trees per block
  int m = lane & 15, q = lane >> 4;
  int sub = lane >> 3, cpos = lane & 7;
  int rA0 = wid * 32 + m;
  int row_l = threadIdx.x & 127;
  int h = __builtin_amdgcn_readfirstlane((int)(threadIdx.x >> 7));  // wave-uniform half
  int grow = bm0 + row_l;

  f32x4 acc[2][8];
#pragma unroll
  for (int i = 0; i < 2; i++)
#pragma unroll
    for (int j = 0; j < 8; j++) acc[i][j] = f32x4{0.f, 0.f, 0.f, 0.f};

  const unsigned short* Ag = xc + (size_t)bm0 * 512;
  const unsigned short* Bg = twb + (size_t)t0 * 64 * 512;

  for (int ko = 0; ko < 8; ++ko) {
    const unsigned short* Ak = Ag + ko * 64;
    const unsigned short* Bk = Bg + ko * 64;
#pragma unroll
    for (int i = 0; i < 4; i++) {
      int seg = wid * 4 + i;
      int r = seg * 8 + sub;
      int cg = cpos ^ (r & 7);
      gload_lds16(Ak + r * 512 + cg * 8, As + seg * 1024);
      gload_lds16(Bk + r * 512 + cg * 8, Bs + seg * 1024);
    }
    __syncthreads();
#pragma unroll
    for (int ks = 0; ks < 2; ++ks) {
      bf16x8 af[2];
#pragma unroll
      for (int mi = 0; mi < 2; mi++) af[mi] = frag_ld(As, rA0 + mi * 16, ks * 4 + q);
#pragma unroll
      for (int ni = 0; ni < 8; ni++) {
        bf16x8 bfr = frag_ld(Bs, ni * 16 + m, ks * 4 + q);
#pragma unroll
        for (int mi = 0; mi < 2; mi++)
          acc[mi][ni] = __builtin_amdgcn_mfma_f32_16x16x32_bf16(af[mi], bfr, acc[mi][ni], 0, 0, 0);
      }
    }
    __syncthreads();
  }

  // ---- epilogue ----
  bool miss = flags[grow] != 0.f;
  float pc[10];
#pragma unroll
  for (int c = 0; c < 10; c++) pc[c] = 0.f;

  for (int tt = 0; tt < 2; ++tt) {
    int t = t0 + tt;
    float itemp = 1.f / tree_temp[t];
    float tbv[4];
#pragma unroll
    for (int nl = 0; nl < 4; nl++) {
      int node = nl * 16 + m;
      tbv[nl] = (node < 63) ? tree_b[t * 63 + node] : 0.f;
    }
    __syncthreads();  // previous readers of decw (GEMM tiles / routing) done
    // sigmoid decisions -> LDS, level-grouped offset node+1
#pragma unroll
    for (int mi = 0; mi < 2; mi++) {
#pragma unroll
      for (int nl = 0; nl < 4; nl++) {
        int node = nl * 16 + m;
        f32x4 a = acc[mi][tt * 4 + nl];
#pragma unroll
        for (int r4 = 0; r4 < 4; r4++) {
          int row = wid * 32 + mi * 16 + q * 4 + r4;
          float z = (a[r4] + tbv[nl]) * itemp;
          decw[row * DSTRIDE + node + 1] = __builtin_amdgcn_rcpf(1.f + __expf(-z));
        }
      }
    }
    __syncthreads();

    const float* dr = decw + row_l * DSTRIDE;
    float R[16];
    {
      float d0 = dr[1];
      d0 = miss ? 0.5f : d0;
      R[0] = d0;
      R[1] = 1.f - d0;
    }
#pragma unroll
    for (int L = 1; L <= 3; ++L) {
      int half = 1 << L;
#pragma unroll
      for (int g = 0; g < half; g += 2) {
        float2 dd = *reinterpret_cast<const float2*>(dr + half + g);
        float da = miss ? 0.5f : dd.x;
        float db = miss ? 0.5f : dd.y;
        float ra = R[g] * da;
        R[g + half] = R[g] - ra;
        R[g] = ra;
        float rb = R[g + 1] * db;
        R[g + 1 + half] = R[g + 1] - rb;
        R[g + 1] = rb;
      }
    }
    // level 4: keep only children with bit4 == h
#pragma unroll
    for (int p = 0; p < 16; p += 2) {
      float2 dd = *reinterpret_cast<const float2*>(dr + 16 + p);
      float da = miss ? 0.5f : dd.x;
      float db = miss ? 0.5f : dd.y;
      da = h ? (1.f - da) : da;
      db = h ? (1.f - db) : db;
      R[p] *= da;
      R[p + 1] *= db;
    }
    // level 5 + leaf dot; leaf indices wave-uniform -> SGPR loads (0 VGPR cost)
    float a10[10];
#pragma unroll
    for (int c = 0; c < 10; c++) a10[c] = 0.f;
    const float* Lf = leaf + (size_t)(t * 64 + 16 * h) * 10;
#pragma unroll
    for (int p = 0; p < 16; p += 2) {
      float2 dd = *reinterpret_cast<const float2*>(dr + 32 + 16 * h + p);
      float da = miss ? 0.5f : dd.x;
      float db = miss ? 0.5f : dd.y;
      float rla = R[p] * da, rra = R[p] - rla;
      float rlb = R[p + 1] * db, rrb = R[p + 1] - rlb;
#pragma unroll
      for (int c = 0; c < 10; c++) {
        float s = fmaf(rla, Lf[p * 10 + c], a10[c]);
        s = fmaf(rra, Lf[320 + p * 10 + c], s);
        s = fmaf(rlb, Lf[p * 10 + 10 + c], s);
        a10[c] = fmaf(rrb, Lf[330 + p * 10 + c], s);
      }
    }
    float w = wbt[grow * 64 + t];
#pragma unroll
    for (int c = 0; c < 10; c++) pc[c] = fmaf(w, a10[c], pc[c]);
  }

  // ---- combine halves in LDS, one non-atomic bf16 partial row per block ----
  __syncthreads();
  float* redbuf = reinterpret_cast<float*>(smem);  // 128 x 10 f32
  if (h == 1) {
#pragma unroll
    for (int c = 0; c < 10; c++) redbuf[row_l * 10 + c] = pc[c];
  }
  __syncthreads();
  if (h == 0) {
    unsigned short* po = part + ((size_t)grow * 32 + blockIdx.y) * 10;
    unsigned wdw[5];
#pragma unroll
    for (int k = 0; k < 5; k++) {
      unsigned lo = f2bf(pc[2 * k] + redbuf[row_l * 10 + 2 * k]);
      unsigned hi = f2bf(pc[2 * k + 1] + redbuf[row_l * 10 + 2 * k + 1]);
      wdw[k] = lo | (hi << 16);
    }
    unsigned* pu = reinterpret_cast<unsigned*>(po);
#pragma unroll
    for (int k = 0; k < 5; k++) pu[k] = wdw[k];
  }
}

// ---------------- final: reduce 32 bf16 slices + softmax ----------------
__global__ void __launch_bounds__(256) k_finish(const unsigned short* __restrict__ part,
                                               float* __restrict__ out) {
  int row = blockIdx.x * 256 + threadIdx.x;
  const unsigned* pu = reinterpret_cast<const unsigned*>(part) + (size_t)row * 160;
  float v[10];
#pragma unroll
  for (int c = 0; c < 10; c++) v[c] = 0.f;
#pragma unroll 4
  for (int s = 0; s < 32; ++s) {
#pragma unroll
    for (int k = 0; k < 5; k++) {
      unsigned wv = pu[s * 5 + k];
      v[2 * k] += bflo(wv);
      v[2 * k + 1] += bfhi(wv);
    }
  }
  float mx = -1e30f;
#pragma unroll
  for (int c = 0; c < 10; c++) mx = fmaxf(mx, v[c]);
  float sm = 0.f;
#pragma unroll
  for (int c = 0; c < 10; c++) {
    v[c] = __expf(v[c] - mx);
    sm += v[c];
  }
  float inv = 1.f / sm;
#pragma unroll
  for (int c = 0; c < 10; c++) out[row * 10 + c] = v[c] * inv;
}

extern "C" void kernel_launch(void* const* d_in, const int* in_sizes, int n_in,
                              void* d_out, int out_size, void* d_ws, size_t ws_size,
                              hipStream_t stream) {
  const float* x    = (const float*)d_in[0];
  const float* w1   = (const float*)d_in[1];
  const float* b1   = (const float*)d_in[2];
  const float* gam  = (const float*)d_in[3];
  const float* bet  = (const float*)d_in[4];
  const float* mu   = (const float*)d_in[5];
  const float* var  = (const float*)d_in[6];
  const float* w2   = (const float*)d_in[7];
  const float* b2   = (const float*)d_in[8];
  const float* tw   = (const float*)d_in[9];
  const float* tb   = (const float*)d_in[10];
  const float* temp = (const float*)d_in[11];
  const float* leaf = (const float*)d_in[12];
  const float* rw   = (const float*)d_in[13];
  float* out = (float*)d_out;

  char* ws = (char*)d_ws;
  unsigned short* xc  = (unsigned short*)(ws);             // 16,777,216 B
  unsigned short* twb = (unsigned short*)(ws + 16777216);  //  4,194,304 B
  unsigned short* w1t = (unsigned short*)(ws + 20971520);  //    131,072 B
  float* wbt  = (float*)(ws + 21102592);                   //  4,194,304 B
  float* flg  = (float*)(ws + 25296896);                   //     65,536 B
  float* h    = (float*)(ws + 25362432);                   //  8,388,608 B (dead after attn2)
  unsigned short* part = (unsigned short*)(ws + 25362432); // 10,485,760 B (overlaps h)

  k_prep<<<5376, 256, 0, stream>>>(x, xc, flg, tw, twb, w1, w1t);
  k_attn1<<<256, 256, 0, stream>>>(xc, w1t, b1, gam, bet, mu, var, h);
  k_attn2<<<1024, 256, 0, stream>>>(h, w2, b2, rw, wbt);
  dim3 g2(128, 32);
  k_trees<<<g2, 256, 0, stream>>>(xc, twb, tb, temp, leaf, wbt, flg, part);
  k_finish<<<64, 256, 0, stream>>>(part, out);
}

// Round 7
// 317.223 us; speedup vs baseline: 1.2875x; 1.0144x over previous
//
#include <hip/hip_runtime.h>
#include <stdint.h>

#define IN_DIM 512
#define NT 64
#define AH 128
#define NCLS 10
#define BN_EPS_C 1e-5f
#define SHRINK 0.3f
#define DSTRIDE 67  // decw leading dim (67%32=3 coprime -> 2-way-free banking)

typedef __bf16 bf16x8 __attribute__((ext_vector_type(8)));
typedef float f32x4 __attribute__((ext_vector_type(4)));
typedef unsigned int u32x4 __attribute__((ext_vector_type(4)));

__device__ __forceinline__ unsigned short f2bf(float f) {
  unsigned u = __builtin_bit_cast(unsigned, f);
  u += 0x7fffu + ((u >> 16) & 1u);   // RNE; inputs are NaN-free after NaN-zeroing
  return (unsigned short)(u >> 16);
}

__device__ __forceinline__ float bflo(unsigned w) {
  return __builtin_bit_cast(float, w << 16);
}
__device__ __forceinline__ float bfhi(unsigned w) {
  return __builtin_bit_cast(float, w & 0xffff0000u);
}

__device__ __forceinline__ void gload_lds16(const void* g, void* l) {
  __builtin_amdgcn_global_load_lds(
      (const __attribute__((address_space(1))) void*)g,
      (__attribute__((address_space(3))) void*)l, 16, 0, 0);
}

// read one 16B MFMA fragment from a swizzled [rows][64] bf16 LDS tile
__device__ __forceinline__ bf16x8 frag_ld(const char* lds, int r, int q) {
  return *reinterpret_cast<const bf16x8*>(lds + r * 128 + ((q ^ (r & 7)) * 16));
}

// ---------------- fused prep: x->bf16+flags, tree_w->bf16(pad), w1->w1t ----
__global__ void __launch_bounds__(256) k_prep(
    const float* __restrict__ x, unsigned short* __restrict__ xc, float* __restrict__ flags,
    const float* __restrict__ tw, unsigned short* __restrict__ twb,
    const float* __restrict__ w1, unsigned short* __restrict__ w1t) {
  int b = blockIdx.x;
  if (b < 4096) {
    int wid = threadIdx.x >> 6, lane = threadIdx.x & 63;
    int row = b * 4 + wid;
    const float* px = x + row * IN_DIM + lane * 8;
    float4 a = *(const float4*)px;
    float4 bb = *(const float4*)(px + 4);
    float v[8] = {a.x, a.y, a.z, a.w, bb.x, bb.y, bb.z, bb.w};
    bool nan_any = false;
    union { unsigned short s[8]; u32x4 u; } pk;
#pragma unroll
    for (int i = 0; i < 8; i++) {
      bool n = (v[i] != v[i]);
      nan_any |= n;
      pk.s[i] = f2bf(n ? 0.f : v[i]);
    }
    *reinterpret_cast<u32x4*>(xc + row * IN_DIM + lane * 8) = pk.u;
    unsigned long long bal = __ballot(nan_any);
    if (lane == 0) flags[row] = bal ? 1.f : 0.f;
  } else if (b < 5120) {
    int tid = (b - 4096) * 256 + threadIdx.x;  // 262144
    int o = tid * 8;
    int k = o & 511;
    int nt = o >> 9;
    int node = nt & 63, t = nt >> 6;
    union { unsigned short s[8]; u32x4 u; } pk;
    if (node < 63) {
      const float* p = tw + ((t * 63 + node) * 512 + k);
      float4 a = *(const float4*)p, bb = *(const float4*)(p + 4);
      float v[8] = {a.x, a.y, a.z, a.w, bb.x, bb.y, bb.z, bb.w};
#pragma unroll
      for (int i = 0; i < 8; i++) pk.s[i] = f2bf(v[i]);
    } else {
#pragma unroll
      for (int i = 0; i < 8; i++) pk.s[i] = 0;
    }
    *reinterpret_cast<u32x4*>(twb + o) = pk.u;
  } else {
    int tid = (b - 5120) * 256 + threadIdx.x;  // 65536
    int k = tid & 511, n = tid >> 9;
    w1t[n * 512 + k] = f2bf(w1[k * 128 + n]);
  }
}

// ---------------- attention ----------------

// h = BN(relu(x@w1 + b1)) : M=16384 N=128 K=512, tile 64x128
__global__ void __launch_bounds__(256) k_attn1(
    const unsigned short* __restrict__ xc, const unsigned short* __restrict__ w1t,
    const float* __restrict__ b1, const float* __restrict__ gam,
    const float* __restrict__ bet, const float* __restrict__ mu,
    const float* __restrict__ var, float* __restrict__ h) {
  __shared__ __align__(16) char smem[24576];
  char* As = smem;          // 64x64 bf16 = 8192
  char* Bs = smem + 8192;   // 128x64 bf16 = 16384
  int lane = threadIdx.x & 63, wid = threadIdx.x >> 6;
  int bm0 = blockIdx.x * 64;
  int m = lane & 15, q = lane >> 4;
  int sub = lane >> 3, cpos = lane & 7;
  f32x4 acc[8];
#pragma unroll
  for (int j = 0; j < 8; j++) acc[j] = f32x4{0.f, 0.f, 0.f, 0.f};
  const unsigned short* Ag = xc + (size_t)bm0 * 512;

  for (int ko = 0; ko < 8; ++ko) {
    const unsigned short* Ak = Ag + ko * 64;
    const unsigned short* Bk = w1t + ko * 64;
#pragma unroll
    for (int i = 0; i < 2; i++) {
      int seg = wid * 2 + i;
      int r = seg * 8 + sub;
      int cg = cpos ^ (r & 7);
      gload_lds16(Ak + r * 512 + cg * 8, As + seg * 1024);
    }
#pragma unroll
    for (int i = 0; i < 4; i++) {
      int seg = wid * 4 + i;
      int r = seg * 8 + sub;
      int cg = cpos ^ (r & 7);
      gload_lds16(Bk + r * 512 + cg * 8, Bs + seg * 1024);
    }
    __syncthreads();
#pragma unroll
    for (int ks = 0; ks < 2; ++ks) {
      bf16x8 af = frag_ld(As, wid * 16 + m, ks * 4 + q);
#pragma unroll
      for (int ni = 0; ni < 8; ni++) {
        bf16x8 bfr = frag_ld(Bs, ni * 16 + m, ks * 4 + q);
        acc[ni] = __builtin_amdgcn_mfma_f32_16x16x32_bf16(af, bfr, acc[ni], 0, 0, 0);
      }
    }
    __syncthreads();
  }
#pragma unroll
  for (int ni = 0; ni < 8; ni++) {
    int col = ni * 16 + m;
    float bb = b1[col], ga = gam[col], be = bet[col], mm = mu[col];
    float iv = rsqrtf(var[col] + BN_EPS_C);
#pragma unroll
    for (int r4 = 0; r4 < 4; r4++) {
      int row = bm0 + wid * 16 + q * 4 + r4;
      float v = acc[ni][r4] + bb;
      v = fmaxf(v, 0.f);
      v = (v - mm) * iv * ga + be;
      h[row * AH + col] = v;
    }
  }
}

// attn = softmax(h@w2 + b2); wbt = attn * SHRINK * rw
// 64 rows/block; NO per-row barriers (hs is wave-private; same-wave LDS RAW
// is ordered by compiler lgkmcnt).
__global__ void __launch_bounds__(256) k_attn2(
    const float* __restrict__ h, const float* __restrict__ w2,
    const float* __restrict__ b2, const float* __restrict__ rw,
    float* __restrict__ wbt) {
  __shared__ float w2s[AH * NT];
  __shared__ float hs[4][AH];
  int lane = threadIdx.x & 63, wid = threadIdx.x >> 6;
  for (int i = threadIdx.x; i < AH * NT; i += 256) w2s[i] = w2[i];
  __syncthreads();
  float bb = b2[lane];
  float cf = SHRINK * rw[lane];
  for (int rr = 0; rr < 16; ++rr) {
    int row = blockIdx.x * 64 + wid * 16 + rr;
    float2 hv = *(const float2*)(h + row * AH + lane * 2);
    hs[wid][lane * 2] = hv.x;
    hs[wid][lane * 2 + 1] = hv.y;
    float s = bb;
#pragma unroll 8
    for (int k = 0; k < AH; k++) s = fmaf(hs[wid][k], w2s[k * NT + lane], s);
    float mx = s;
#pragma unroll
    for (int o = 1; o < 64; o <<= 1) mx = fmaxf(mx, __shfl_xor(mx, o));
    float e = __expf(s - mx);
    float sm = e;
#pragma unroll
    for (int o = 1; o < 64; o <<= 1) sm += __shfl_xor(sm, o);
    wbt[row * NT + lane] = (e / sm) * cf;
  }
}

// ---------------- main: tree logits + routing + leaf -> per-slice partials ----
// tile: 128 rows x 128 cols (2 trees), BK=64, 4 waves, SINGLE GEMM pass.
// Grid: x = tree-pair (fast), y = row-tile -> 32 co-dispatched blocks share one
// A-tile and twb fits per-XCD L2 (R6 had x/y swapped: FETCH 107 MB, A re-read 6x).
// Epilogue: decisions via LDS (stride 67); miss folded in at WRITE time; leaf
// values via wave-uniform global reads -> SGPRs (92-96 VGPR regime; R5's
// LDS-float4 leaf reads blew it to 216 VGPR -> 1 block/CU).
// NO atomics (R3: 10.5M device atomics = +300 MB WRITE, serialized at L3).
// NOTE: no min-waves arg in launch_bounds (R2: VGPR cap 64 -> spill -> 1.6x).
__global__ void __launch_bounds__(256) k_trees(
    const unsigned short* __restrict__ xc,   // [16384][512]
    const unsigned short* __restrict__ twb,  // [64*64][512]
    const float* __restrict__ tree_b,        // [64][63]
    const float* __restrict__ tree_temp,     // [64]
    const float* __restrict__ leaf,          // [64][64][10]
    const float* __restrict__ wbt,           // [16384][64]
    const float* __restrict__ flags,         // [16384]
    unsigned short* __restrict__ part) {     // [16384][32][10] bf16
  __shared__ __align__(16) char smem[34816];
  char* As = smem;                                  // 128x64 bf16 = 16384
  char* Bs = smem + 16384;                          // 128x64 bf16 = 16384
  float* decw = reinterpret_cast<float*>(smem);     // 128 x 67 f32 = 34304 (epilogue)
  int lane = threadIdx.x & 63, wid = threadIdx.x >> 6;
  int bm0 = blockIdx.y * 128;   // row tile
  int t0 = blockIdx.x * 2;      // tree pair (fast grid dim for L2 sharing)
  int m = lane & 15, q = lane >> 4;
  int sub = lane >> 3, cpos = lane & 7;
  int rA0 = wid * 32 + m;
  int row_l = threadIdx.x & 127;
  int h = __builtin_amdgcn_readfirstlane((int)(threadIdx.x >> 7));  // wave-uniform half
  int grow = bm0 + row_l;

  f32x4 acc[2][8];
#pragma unroll
  for (int i = 0; i < 2; i++)
#pragma unroll
    for (int j = 0; j < 8; j++) acc[i][j] = f32x4{0.f, 0.f, 0.f, 0.f};

  const unsigned short* Ag = xc + (size_t)bm0 * 512;
  const unsigned short* Bg = twb + (size_t)t0 * 64 * 512;

  for (int ko = 0; ko < 8; ++ko) {
    const unsigned short* Ak = Ag + ko * 64;
    const unsigned short* Bk = Bg + ko * 64;
#pragma unroll
    for (int i = 0; i < 4; i++) {
      int seg = wid * 4 + i;
      int r = seg * 8 + sub;
      int cg = cpos ^ (r & 7);
      gload_lds16(Ak + r * 512 + cg * 8, As + seg * 1024);
      gload_lds16(Bk + r * 512 + cg * 8, Bs + seg * 1024);
    }
    __syncthreads();
#pragma unroll
    for (int ks = 0; ks < 2; ++ks) {
      bf16x8 af[2];
#pragma unroll
      for (int mi = 0; mi < 2; mi++) af[mi] = frag_ld(As, rA0 + mi * 16, ks * 4 + q);
#pragma unroll
      for (int ni = 0; ni < 8; ni++) {
        bf16x8 bfr = frag_ld(Bs, ni * 16 + m, ks * 4 + q);
#pragma unroll
        for (int mi = 0; mi < 2; mi++)
          acc[mi][ni] = __builtin_amdgcn_mfma_f32_16x16x32_bf16(af[mi], bfr, acc[mi][ni], 0, 0, 0);
      }
    }
    __syncthreads();
  }

  // ---- epilogue ----
  // flags for the 8 rows this thread WRITES (miss folded in at write time)
  float flv[2][4];
  {
    float4 f0 = *(const float4*)(flags + bm0 + wid * 32 + q * 4);
    float4 f1 = *(const float4*)(flags + bm0 + wid * 32 + 16 + q * 4);
    flv[0][0] = f0.x; flv[0][1] = f0.y; flv[0][2] = f0.z; flv[0][3] = f0.w;
    flv[1][0] = f1.x; flv[1][1] = f1.y; flv[1][2] = f1.z; flv[1][3] = f1.w;
  }
  float2 wpair = *(const float2*)(wbt + grow * 64 + t0);  // prefetch weights
  float pc[10];
#pragma unroll
  for (int c = 0; c < 10; c++) pc[c] = 0.f;

  for (int tt = 0; tt < 2; ++tt) {
    int t = t0 + tt;
    float itemp = 1.f / tree_temp[t];
    float tbv[4];
#pragma unroll
    for (int nl = 0; nl < 4; nl++) {
      int node = nl * 16 + m;
      tbv[nl] = (node < 63) ? tree_b[t * 63 + node] : 0.f;
    }
    __syncthreads();  // previous readers of decw (GEMM tiles / routing) done
    // sigmoid decisions -> LDS, level-grouped offset node+1, miss applied here
#pragma unroll
    for (int mi = 0; mi < 2; mi++) {
#pragma unroll
      for (int nl = 0; nl < 4; nl++) {
        int node = nl * 16 + m;
        f32x4 a = acc[mi][tt * 4 + nl];
#pragma unroll
        for (int r4 = 0; r4 < 4; r4++) {
          int row = wid * 32 + mi * 16 + q * 4 + r4;
          float z = (a[r4] + tbv[nl]) * itemp;
          float sig = __builtin_amdgcn_rcpf(1.f + __expf(-z));
          decw[row * DSTRIDE + node + 1] = (flv[mi][r4] != 0.f) ? 0.5f : sig;
        }
      }
    }
    __syncthreads();

    const float* dr = decw + row_l * DSTRIDE;
    float R[16];
    {
      float d0 = dr[1];
      R[0] = d0;
      R[1] = 1.f - d0;
    }
#pragma unroll
    for (int L = 1; L <= 3; ++L) {
      int half = 1 << L;
#pragma unroll
      for (int g = 0; g < half; g += 2) {
        float2 dd = *reinterpret_cast<const float2*>(dr + half + g);
        float ra = R[g] * dd.x;
        R[g + half] = R[g] - ra;
        R[g] = ra;
        float rb = R[g + 1] * dd.y;
        R[g + 1 + half] = R[g + 1] - rb;
        R[g + 1] = rb;
      }
    }
    // level 4: keep only children with bit4 == h
#pragma unroll
    for (int p = 0; p < 16; p += 2) {
      float2 dd = *reinterpret_cast<const float2*>(dr + 16 + p);
      float da = h ? (1.f - dd.x) : dd.x;
      float db = h ? (1.f - dd.y) : dd.y;
      R[p] *= da;
      R[p + 1] *= db;
    }
    // level 5 + leaf dot; leaf indices wave-uniform -> SGPR loads (0 VGPR cost)
    float a10[10];
#pragma unroll
    for (int c = 0; c < 10; c++) a10[c] = 0.f;
    const float* Lf = leaf + (size_t)(t * 64 + 16 * h) * 10;
#pragma unroll
    for (int p = 0; p < 16; p += 2) {
      float2 dd = *reinterpret_cast<const float2*>(dr + 32 + 16 * h + p);
      float rla = R[p] * dd.x, rra = R[p] - rla;
      float rlb = R[p + 1] * dd.y, rrb = R[p + 1] - rlb;
#pragma unroll
      for (int c = 0; c < 10; c++) {
        float s = fmaf(rla, Lf[p * 10 + c], a10[c]);
        s = fmaf(rra, Lf[320 + p * 10 + c], s);
        s = fmaf(rlb, Lf[p * 10 + 10 + c], s);
        a10[c] = fmaf(rrb, Lf[330 + p * 10 + c], s);
      }
    }
    float w = tt ? wpair.y : wpair.x;
#pragma unroll
    for (int c = 0; c < 10; c++) pc[c] = fmaf(w, a10[c], pc[c]);
  }

  // ---- combine halves in LDS, one non-atomic bf16 partial row per block ----
  __syncthreads();
  float* redbuf = reinterpret_cast<float*>(smem);  // 128 x 10 f32
  if (h == 1) {
#pragma unroll
    for (int c = 0; c < 10; c++) redbuf[row_l * 10 + c] = pc[c];
  }
  __syncthreads();
  if (h == 0) {
    unsigned short* po = part + ((size_t)grow * 32 + blockIdx.x) * 10;
    unsigned wdw[5];
#pragma unroll
    for (int k = 0; k < 5; k++) {
      unsigned lo = f2bf(pc[2 * k] + redbuf[row_l * 10 + 2 * k]);
      unsigned hi = f2bf(pc[2 * k + 1] + redbuf[row_l * 10 + 2 * k + 1]);
      wdw[k] = lo | (hi << 16);
    }
    unsigned* pu = reinterpret_cast<unsigned*>(po);
#pragma unroll
    for (int k = 0; k < 5; k++) pu[k] = wdw[k];
  }
}

// ---------------- final: reduce 32 bf16 slices + softmax ----------------
__global__ void __launch_bounds__(64) k_finish(const unsigned short* __restrict__ part,
                                              float* __restrict__ out) {
  int row = blockIdx.x * 64 + threadIdx.x;
  const unsigned* pu = reinterpret_cast<const unsigned*>(part) + (size_t)row * 160;
  float v[10];
#pragma unroll
  for (int c = 0; c < 10; c++) v[c] = 0.f;
#pragma unroll 4
  for (int s = 0; s < 32; ++s) {
#pragma unroll
    for (int k = 0; k < 5; k++) {
      unsigned wv = pu[s * 5 + k];
      v[2 * k] += bflo(wv);
      v[2 * k + 1] += bfhi(wv);
    }
  }
  float mx = -1e30f;
#pragma unroll
  for (int c = 0; c < 10; c++) mx = fmaxf(mx, v[c]);
  float sm = 0.f;
#pragma unroll
  for (int c = 0; c < 10; c++) {
    v[c] = __expf(v[c] - mx);
    sm += v[c];
  }
  float inv = 1.f / sm;
#pragma unroll
  for (int c = 0; c < 10; c++) out[row * 10 + c] = v[c] * inv;
}

extern "C" void kernel_launch(void* const* d_in, const int* in_sizes, int n_in,
                              void* d_out, int out_size, void* d_ws, size_t ws_size,
                              hipStream_t stream) {
  const float* x    = (const float*)d_in[0];
  const float* w1   = (const float*)d_in[1];
  const float* b1   = (const float*)d_in[2];
  const float* gam  = (const float*)d_in[3];
  const float* bet  = (const float*)d_in[4];
  const float* mu   = (const float*)d_in[5];
  const float* var  = (const float*)d_in[6];
  const float* w2   = (const float*)d_in[7];
  const float* b2   = (const float*)d_in[8];
  const float* tw   = (const float*)d_in[9];
  const float* tb   = (const float*)d_in[10];
  const float* temp = (const float*)d_in[11];
  const float* leaf = (const float*)d_in[12];
  const float* rw   = (const float*)d_in[13];
  float* out = (float*)d_out;

  char* ws = (char*)d_ws;
  unsigned short* xc  = (unsigned short*)(ws);             // 16,777,216 B
  unsigned short* twb = (unsigned short*)(ws + 16777216);  //  4,194,304 B
  unsigned short* w1t = (unsigned short*)(ws + 20971520);  //    131,072 B
  float* wbt  = (float*)(ws + 21102592);                   //  4,194,304 B
  float* flg  = (float*)(ws + 25296896);                   //     65,536 B
  float* h    = (float*)(ws + 25362432);                   //  8,388,608 B (dead after attn2)
  unsigned short* part = (unsigned short*)(ws + 25362432); // 10,485,760 B (overlaps h)

  k_prep<<<5376, 256, 0, stream>>>(x, xc, flg, tw, twb, w1, w1t);
  k_attn1<<<256, 256, 0, stream>>>(xc, w1t, b1, gam, bet, mu, var, h);
  k_attn2<<<256, 256, 0, stream>>>(h, w2, b2, rw, wbt);
  dim3 g2(32, 128);
  k_trees<<<g2, 256, 0, stream>>>(xc, twb, tb, temp, leaf, wbt, flg, part);
  k_finish<<<256, 64, 0, stream>>>(part, out);
}

// Round 8
// 290.772 us; speedup vs baseline: 1.4046x; 1.0910x over previous
//
#include <hip/hip_runtime.h>
#include <stdint.h>

#define IN_DIM 512
#define NT 64
#define AH 128
#define NCLS 10
#define BN_EPS_C 1e-5f
#define SHRINK 0.3f
#define DSTRIDE 67  // decw leading dim (67%32=3 coprime -> 2-way-free banking)

typedef __bf16 bf16x8 __attribute__((ext_vector_type(8)));
typedef float f32x4 __attribute__((ext_vector_type(4)));
typedef unsigned int u32x4 __attribute__((ext_vector_type(4)));

__device__ __forceinline__ unsigned short f2bf(float f) {
  unsigned u = __builtin_bit_cast(unsigned, f);
  u += 0x7fffu + ((u >> 16) & 1u);   // RNE; inputs are NaN-free after NaN-zeroing
  return (unsigned short)(u >> 16);
}

__device__ __forceinline__ float bflo(unsigned w) {
  return __builtin_bit_cast(float, w << 16);
}
__device__ __forceinline__ float bfhi(unsigned w) {
  return __builtin_bit_cast(float, w & 0xffff0000u);
}

__device__ __forceinline__ void gload_lds16(const void* g, void* l) {
  __builtin_amdgcn_global_load_lds(
      (const __attribute__((address_space(1))) void*)g,
      (__attribute__((address_space(3))) void*)l, 16, 0, 0);
}

// read one 16B MFMA fragment from a swizzled [rows][64] bf16 LDS tile
__device__ __forceinline__ bf16x8 frag_ld(const char* lds, int r, int q) {
  return *reinterpret_cast<const bf16x8*>(lds + r * 128 + ((q ^ (r & 7)) * 16));
}

// ---------------- fused prep: x->bf16+flags, tree_w->bf16(pad), w1->w1t ----
__global__ void __launch_bounds__(256) k_prep(
    const float* __restrict__ x, unsigned short* __restrict__ xc, float* __restrict__ flags,
    const float* __restrict__ tw, unsigned short* __restrict__ twb,
    const float* __restrict__ w1, unsigned short* __restrict__ w1t) {
  int b = blockIdx.x;
  if (b < 4096) {
    int wid = threadIdx.x >> 6, lane = threadIdx.x & 63;
    int row = b * 4 + wid;
    const float* px = x + row * IN_DIM + lane * 8;
    float4 a = *(const float4*)px;
    float4 bb = *(const float4*)(px + 4);
    float v[8] = {a.x, a.y, a.z, a.w, bb.x, bb.y, bb.z, bb.w};
    bool nan_any = false;
    union { unsigned short s[8]; u32x4 u; } pk;
#pragma unroll
    for (int i = 0; i < 8; i++) {
      bool n = (v[i] != v[i]);
      nan_any |= n;
      pk.s[i] = f2bf(n ? 0.f : v[i]);
    }
    *reinterpret_cast<u32x4*>(xc + row * IN_DIM + lane * 8) = pk.u;
    unsigned long long bal = __ballot(nan_any);
    if (lane == 0) flags[row] = bal ? 1.f : 0.f;
  } else if (b < 5120) {
    int tid = (b - 4096) * 256 + threadIdx.x;  // 262144
    int o = tid * 8;
    int k = o & 511;
    int nt = o >> 9;
    int node = nt & 63, t = nt >> 6;
    union { unsigned short s[8]; u32x4 u; } pk;
    if (node < 63) {
      const float* p = tw + ((t * 63 + node) * 512 + k);
      float4 a = *(const float4*)p, bb = *(const float4*)(p + 4);
      float v[8] = {a.x, a.y, a.z, a.w, bb.x, bb.y, bb.z, bb.w};
#pragma unroll
      for (int i = 0; i < 8; i++) pk.s[i] = f2bf(v[i]);
    } else {
#pragma unroll
      for (int i = 0; i < 8; i++) pk.s[i] = 0;
    }
    *reinterpret_cast<u32x4*>(twb + o) = pk.u;
  } else {
    int tid = (b - 5120) * 256 + threadIdx.x;  // 65536
    int k = tid & 511, n = tid >> 9;
    w1t[n * 512 + k] = f2bf(w1[k * 128 + n]);
  }
}

// ---------------- fused attention: h = BN(relu(x@w1+b1)); attn=softmax(h@w2+b2);
// wbt = attn*SHRINK*rw.  M=16384, tile 64 rows/block.
// GEMM1: MFMA (as before). h-tile kept in LDS as bf16 (per-wave-private region,
// same-wave RAW ordered by compiler lgkmcnt -> no barrier). GEMM2: MFMA vs
// w2 staged to LDS bf16 at block start (covered by K-loop barriers). Row
// softmax via shfl_xor over the 16-lane col group. Kills the separate attn2
// launch (R7: 1 block/CU serial chains) and 16.8 MB of h global round-trip.
__global__ void __launch_bounds__(256) k_attn(
    const unsigned short* __restrict__ xc, const unsigned short* __restrict__ w1t,
    const float* __restrict__ b1, const float* __restrict__ gam,
    const float* __restrict__ bet, const float* __restrict__ mu,
    const float* __restrict__ var, const float* __restrict__ w2,
    const float* __restrict__ b2, const float* __restrict__ rw,
    float* __restrict__ wbt) {
  __shared__ __align__(16) char smem[59392];
  char* As = smem;                                        // 64x64 bf16 = 8192
  char* Bs = smem + 8192;                                 // 128x64 bf16 = 16384
  unsigned short* hb  = (unsigned short*)(smem + 24576);  // [64][136] bf16 = 17408
  unsigned short* w2s = (unsigned short*)(smem + 41984);  // [64][136] bf16 = 17408
  int lane = threadIdx.x & 63, wid = threadIdx.x >> 6;
  int bm0 = blockIdx.x * 64;
  int m = lane & 15, q = lane >> 4;
  int sub = lane >> 3, cpos = lane & 7;

  // stage w2 (transposed, bf16) into LDS; K-loop barrier covers readers
  for (int i = threadIdx.x; i < AH * NT; i += 256) {
    int k = i >> 6, n = i & 63;
    w2s[n * 136 + k] = f2bf(w2[i]);
  }

  f32x4 acc[8];
#pragma unroll
  for (int j = 0; j < 8; j++) acc[j] = f32x4{0.f, 0.f, 0.f, 0.f};
  const unsigned short* Ag = xc + (size_t)bm0 * 512;

  for (int ko = 0; ko < 8; ++ko) {
    const unsigned short* Ak = Ag + ko * 64;
    const unsigned short* Bk = w1t + ko * 64;
#pragma unroll
    for (int i = 0; i < 2; i++) {
      int seg = wid * 2 + i;
      int r = seg * 8 + sub;
      int cg = cpos ^ (r & 7);
      gload_lds16(Ak + r * 512 + cg * 8, As + seg * 1024);
    }
#pragma unroll
    for (int i = 0; i < 4; i++) {
      int seg = wid * 4 + i;
      int r = seg * 8 + sub;
      int cg = cpos ^ (r & 7);
      gload_lds16(Bk + r * 512 + cg * 8, Bs + seg * 1024);
    }
    __syncthreads();
#pragma unroll
    for (int ks = 0; ks < 2; ++ks) {
      bf16x8 af = frag_ld(As, wid * 16 + m, ks * 4 + q);
#pragma unroll
      for (int ni = 0; ni < 8; ni++) {
        bf16x8 bfr = frag_ld(Bs, ni * 16 + m, ks * 4 + q);
        acc[ni] = __builtin_amdgcn_mfma_f32_16x16x32_bf16(af, bfr, acc[ni], 0, 0, 0);
      }
    }
    __syncthreads();
  }

  // epilogue 1: bias/ReLU/BN -> hb (bf16, per-wave rows wid*16..wid*16+15)
#pragma unroll
  for (int ni = 0; ni < 8; ni++) {
    int col = ni * 16 + m;
    float bb = b1[col], ga = gam[col], be = bet[col], mm = mu[col];
    float iv = rsqrtf(var[col] + BN_EPS_C);
#pragma unroll
    for (int r4 = 0; r4 < 4; r4++) {
      int rl = wid * 16 + q * 4 + r4;
      float v = acc[ni][r4] + bb;
      v = fmaxf(v, 0.f);
      v = (v - mm) * iv * ga + be;
      hb[rl * 136 + col] = f2bf(v);
    }
  }

  // GEMM2: s[64 rows][64 trees] = hb @ w2s^T ; per-wave m-tile = its own rows
  f32x4 acc2[4];
#pragma unroll
  for (int nt = 0; nt < 4; nt++) acc2[nt] = f32x4{0.f, 0.f, 0.f, 0.f};
#pragma unroll
  for (int ks = 0; ks < 4; ++ks) {
    bf16x8 af = *reinterpret_cast<const bf16x8*>(hb + (wid * 16 + m) * 136 + ks * 32 + q * 8);
#pragma unroll
    for (int nt = 0; nt < 4; nt++) {
      bf16x8 bfr = *reinterpret_cast<const bf16x8*>(w2s + (nt * 16 + m) * 136 + ks * 32 + q * 8);
      acc2[nt] = __builtin_amdgcn_mfma_f32_16x16x32_bf16(af, bfr, acc2[nt], 0, 0, 0);
    }
  }

  // softmax over 64 trees per row (4 n-tiles in-thread x 16 lanes via shfl_xor)
  float b2v[4], cfv[4];
#pragma unroll
  for (int nt = 0; nt < 4; nt++) {
    int col = nt * 16 + m;
    b2v[nt] = b2[col];
    cfv[nt] = SHRINK * rw[col];
  }
#pragma unroll
  for (int reg = 0; reg < 4; ++reg) {
    float s0 = acc2[0][reg] + b2v[0];
    float s1 = acc2[1][reg] + b2v[1];
    float s2 = acc2[2][reg] + b2v[2];
    float s3 = acc2[3][reg] + b2v[3];
    float mx = fmaxf(fmaxf(s0, s1), fmaxf(s2, s3));
#pragma unroll
    for (int o = 1; o < 16; o <<= 1) mx = fmaxf(mx, __shfl_xor(mx, o));
    float e0 = __expf(s0 - mx), e1 = __expf(s1 - mx);
    float e2 = __expf(s2 - mx), e3 = __expf(s3 - mx);
    float sm = e0 + e1 + e2 + e3;
#pragma unroll
    for (int o = 1; o < 16; o <<= 1) sm += __shfl_xor(sm, o);
    float inv = 1.f / sm;
    int row = bm0 + wid * 16 + q * 4 + reg;
    wbt[row * NT + m]      = e0 * inv * cfv[0];
    wbt[row * NT + 16 + m] = e1 * inv * cfv[1];
    wbt[row * NT + 32 + m] = e2 * inv * cfv[2];
    wbt[row * NT + 48 + m] = e3 * inv * cfv[3];
  }
}

// ---------------- main: tree logits + routing + leaf -> per-slice partials ----
// (UNCHANGED from round 7 — verified 186 us / 96 VGPR.)
// tile: 128 rows x 128 cols (2 trees), BK=64, 4 waves, SINGLE GEMM pass.
// Grid: x = tree-pair (fast), y = row-tile -> co-dispatched blocks share A-tile.
// Epilogue: decisions via LDS (stride 67); miss folded in at WRITE time; leaf
// values via wave-uniform global reads -> SGPRs (R5's LDS-float4 leaf reads
// blew VGPR to 216 -> 1 block/CU). NO atomics (R3). No VGPR cap (R2).
__global__ void __launch_bounds__(256) k_trees(
    const unsigned short* __restrict__ xc,   // [16384][512]
    const unsigned short* __restrict__ twb,  // [64*64][512]
    const float* __restrict__ tree_b,        // [64][63]
    const float* __restrict__ tree_temp,     // [64]
    const float* __restrict__ leaf,          // [64][64][10]
    const float* __restrict__ wbt,           // [16384][64]
    const float* __restrict__ flags,         // [16384]
    unsigned short* __restrict__ part) {     // [16384][32][10] bf16
  __shared__ __align__(16) char smem[34816];
  char* As = smem;                                  // 128x64 bf16 = 16384
  char* Bs = smem + 16384;                          // 128x64 bf16 = 16384
  float* decw = reinterpret_cast<float*>(smem);     // 128 x 67 f32 = 34304 (epilogue)
  int lane = threadIdx.x & 63, wid = threadIdx.x >> 6;
  int bm0 = blockIdx.y * 128;   // row tile
  int t0 = blockIdx.x * 2;      // tree pair (fast grid dim for L2 sharing)
  int m = lane & 15, q = lane >> 4;
  int sub = lane >> 3, cpos = lane & 7;
  int rA0 = wid * 32 + m;
  int row_l = threadIdx.x & 127;
  int h = __builtin_amdgcn_readfirstlane((int)(threadIdx.x >> 7));  // wave-uniform half
  int grow = bm0 + row_l;

  f32x4 acc[2][8];
#pragma unroll
  for (int i = 0; i < 2; i++)
#pragma unroll
    for (int j = 0; j < 8; j++) acc[i][j] = f32x4{0.f, 0.f, 0.f, 0.f};

  const unsigned short* Ag = xc + (size_t)bm0 * 512;
  const unsigned short* Bg = twb + (size_t)t0 * 64 * 512;

  for (int ko = 0; ko < 8; ++ko) {
    const unsigned short* Ak = Ag + ko * 64;
    const unsigned short* Bk = Bg + ko * 64;
#pragma unroll
    for (int i = 0; i < 4; i++) {
      int seg = wid * 4 + i;
      int r = seg * 8 + sub;
      int cg = cpos ^ (r & 7);
      gload_lds16(Ak + r * 512 + cg * 8, As + seg * 1024);
      gload_lds16(Bk + r * 512 + cg * 8, Bs + seg * 1024);
    }
    __syncthreads();
#pragma unroll
    for (int ks = 0; ks < 2; ++ks) {
      bf16x8 af[2];
#pragma unroll
      for (int mi = 0; mi < 2; mi++) af[mi] = frag_ld(As, rA0 + mi * 16, ks * 4 + q);
#pragma unroll
      for (int ni = 0; ni < 8; ni++) {
        bf16x8 bfr = frag_ld(Bs, ni * 16 + m, ks * 4 + q);
#pragma unroll
        for (int mi = 0; mi < 2; mi++)
          acc[mi][ni] = __builtin_amdgcn_mfma_f32_16x16x32_bf16(af[mi], bfr, acc[mi][ni], 0, 0, 0);
      }
    }
    __syncthreads();
  }

  // ---- epilogue ----
  float flv[2][4];
  {
    float4 f0 = *(const float4*)(flags + bm0 + wid * 32 + q * 4);
    float4 f1 = *(const float4*)(flags + bm0 + wid * 32 + 16 + q * 4);
    flv[0][0] = f0.x; flv[0][1] = f0.y; flv[0][2] = f0.z; flv[0][3] = f0.w;
    flv[1][0] = f1.x; flv[1][1] = f1.y; flv[1][2] = f1.z; flv[1][3] = f1.w;
  }
  float2 wpair = *(const float2*)(wbt + grow * 64 + t0);  // prefetch weights
  float pc[10];
#pragma unroll
  for (int c = 0; c < 10; c++) pc[c] = 0.f;

  for (int tt = 0; tt < 2; ++tt) {
    int t = t0 + tt;
    float itemp = 1.f / tree_temp[t];
    float tbv[4];
#pragma unroll
    for (int nl = 0; nl < 4; nl++) {
      int node = nl * 16 + m;
      tbv[nl] = (node < 63) ? tree_b[t * 63 + node] : 0.f;
    }
    __syncthreads();  // previous readers of decw (GEMM tiles / routing) done
#pragma unroll
    for (int mi = 0; mi < 2; mi++) {
#pragma unroll
      for (int nl = 0; nl < 4; nl++) {
        int node = nl * 16 + m;
        f32x4 a = acc[mi][tt * 4 + nl];
#pragma unroll
        for (int r4 = 0; r4 < 4; r4++) {
          int row = wid * 32 + mi * 16 + q * 4 + r4;
          float z = (a[r4] + tbv[nl]) * itemp;
          float sig = __builtin_amdgcn_rcpf(1.f + __expf(-z));
          decw[row * DSTRIDE + node + 1] = (flv[mi][r4] != 0.f) ? 0.5f : sig;
        }
      }
    }
    __syncthreads();

    const float* dr = decw + row_l * DSTRIDE;
    float R[16];
    {
      float d0 = dr[1];
      R[0] = d0;
      R[1] = 1.f - d0;
    }
#pragma unroll
    for (int L = 1; L <= 3; ++L) {
      int half = 1 << L;
#pragma unroll
      for (int g = 0; g < half; g += 2) {
        float2 dd = *reinterpret_cast<const float2*>(dr + half + g);
        float ra = R[g] * dd.x;
        R[g + half] = R[g] - ra;
        R[g] = ra;
        float rb = R[g + 1] * dd.y;
        R[g + 1 + half] = R[g + 1] - rb;
        R[g + 1] = rb;
      }
    }
#pragma unroll
    for (int p = 0; p < 16; p += 2) {
      float2 dd = *reinterpret_cast<const float2*>(dr + 16 + p);
      float da = h ? (1.f - dd.x) : dd.x;
      float db = h ? (1.f - dd.y) : dd.y;
      R[p] *= da;
      R[p + 1] *= db;
    }
    float a10[10];
#pragma unroll
    for (int c = 0; c < 10; c++) a10[c] = 0.f;
    const float* Lf = leaf + (size_t)(t * 64 + 16 * h) * 10;
#pragma unroll
    for (int p = 0; p < 16; p += 2) {
      float2 dd = *reinterpret_cast<const float2*>(dr + 32 + 16 * h + p);
      float rla = R[p] * dd.x, rra = R[p] - rla;
      float rlb = R[p + 1] * dd.y, rrb = R[p + 1] - rlb;
#pragma unroll
      for (int c = 0; c < 10; c++) {
        float s = fmaf(rla, Lf[p * 10 + c], a10[c]);
        s = fmaf(rra, Lf[320 + p * 10 + c], s);
        s = fmaf(rlb, Lf[p * 10 + 10 + c], s);
        a10[c] = fmaf(rrb, Lf[330 + p * 10 + c], s);
      }
    }
    float w = tt ? wpair.y : wpair.x;
#pragma unroll
    for (int c = 0; c < 10; c++) pc[c] = fmaf(w, a10[c], pc[c]);
  }

  __syncthreads();
  float* redbuf = reinterpret_cast<float*>(smem);  // 128 x 10 f32
  if (h == 1) {
#pragma unroll
    for (int c = 0; c < 10; c++) redbuf[row_l * 10 + c] = pc[c];
  }
  __syncthreads();
  if (h == 0) {
    unsigned short* po = part + ((size_t)grow * 32 + blockIdx.x) * 10;
    unsigned wdw[5];
#pragma unroll
    for (int k = 0; k < 5; k++) {
      unsigned lo = f2bf(pc[2 * k] + redbuf[row_l * 10 + 2 * k]);
      unsigned hi = f2bf(pc[2 * k + 1] + redbuf[row_l * 10 + 2 * k + 1]);
      wdw[k] = lo | (hi << 16);
    }
    unsigned* pu = reinterpret_cast<unsigned*>(po);
#pragma unroll
    for (int k = 0; k < 5; k++) pu[k] = wdw[k];
  }
}

// ---------------- final: reduce 32 bf16 slices + softmax ----------------
// 40 independent uint4 loads per row (8 chunks of 5 = 4 slices each) -> MLP.
__global__ void __launch_bounds__(256) k_finish(const unsigned short* __restrict__ part,
                                               float* __restrict__ out) {
  int row = blockIdx.x * 256 + threadIdx.x;
  const uint4* pu = reinterpret_cast<const uint4*>(part + (size_t)row * 320);
  float v[10];
#pragma unroll
  for (int c = 0; c < 10; c++) v[c] = 0.f;
#pragma unroll
  for (int ch = 0; ch < 8; ++ch) {
    uint4 w0 = pu[ch * 5 + 0];
    uint4 w1 = pu[ch * 5 + 1];
    uint4 w2 = pu[ch * 5 + 2];
    uint4 w3 = pu[ch * 5 + 3];
    uint4 w4 = pu[ch * 5 + 4];
    unsigned dw[20] = {w0.x, w0.y, w0.z, w0.w, w1.x, w1.y, w1.z, w1.w,
                       w2.x, w2.y, w2.z, w2.w, w3.x, w3.y, w3.z, w3.w,
                       w4.x, w4.y, w4.z, w4.w};
#pragma unroll
    for (int d = 0; d < 20; d++) {
      int k = d % 5;
      v[2 * k] += bflo(dw[d]);
      v[2 * k + 1] += bfhi(dw[d]);
    }
  }
  float mx = -1e30f;
#pragma unroll
  for (int c = 0; c < 10; c++) mx = fmaxf(mx, v[c]);
  float sm = 0.f;
#pragma unroll
  for (int c = 0; c < 10; c++) {
    v[c] = __expf(v[c] - mx);
    sm += v[c];
  }
  float inv = 1.f / sm;
#pragma unroll
  for (int c = 0; c < 10; c++) out[row * 10 + c] = v[c] * inv;
}

extern "C" void kernel_launch(void* const* d_in, const int* in_sizes, int n_in,
                              void* d_out, int out_size, void* d_ws, size_t ws_size,
                              hipStream_t stream) {
  const float* x    = (const float*)d_in[0];
  const float* w1   = (const float*)d_in[1];
  const float* b1   = (const float*)d_in[2];
  const float* gam  = (const float*)d_in[3];
  const float* bet  = (const float*)d_in[4];
  const float* mu   = (const float*)d_in[5];
  const float* var  = (const float*)d_in[6];
  const float* w2   = (const float*)d_in[7];
  const float* b2   = (const float*)d_in[8];
  const float* tw   = (const float*)d_in[9];
  const float* tb   = (const float*)d_in[10];
  const float* temp = (const float*)d_in[11];
  const float* leaf = (const float*)d_in[12];
  const float* rw   = (const float*)d_in[13];
  float* out = (float*)d_out;

  char* ws = (char*)d_ws;
  unsigned short* xc  = (unsigned short*)(ws);             // 16,777,216 B
  unsigned short* twb = (unsigned short*)(ws + 16777216);  //  4,194,304 B
  unsigned short* w1t = (unsigned short*)(ws + 20971520);  //    131,072 B
  float* wbt  = (float*)(ws + 21102592);                   //  4,194,304 B
  float* flg  = (float*)(ws + 25296896);                   //     65,536 B
  unsigned short* part = (unsigned short*)(ws + 25362432); // 10,485,760 B

  k_prep<<<5376, 256, 0, stream>>>(x, xc, flg, tw, twb, w1, w1t);
  k_attn<<<256, 256, 0, stream>>>(xc, w1t, b1, gam, bet, mu, var, w2, b2, rw, wbt);
  dim3 g2(32, 128);
  k_trees<<<g2, 256, 0, stream>>>(xc, twb, tb, temp, leaf, wbt, flg, part);
  k_finish<<<64, 256, 0, stream>>>(part, out);
}